// Round 1
// 827.119 us; speedup vs baseline: 1.0192x; 1.0192x over previous
//
#include <hip/hip_runtime.h>

// MoE grouped experts: E=16, H=2048, I=1408, TOPK=4, B*S=2048 tokens, P=8192 rows.
// fp32 in/out; compute in fp16 MFMA (16x16x32), fp32 accumulate.

#define NE   16
#define HD   2048
#define ID   1408
#define NTOK 2048
#define NP   8192
#define MAXT 96

typedef _Float16 f16x8 __attribute__((ext_vector_type(8)));
typedef float    f32x4 __attribute__((ext_vector_type(4)));
typedef unsigned short u16;
typedef u16      u16x8 __attribute__((ext_vector_type(8)));

__device__ __forceinline__ u16 f2hu(float f) {
  _Float16 h = (_Float16)f;               // RNE
  return __builtin_bit_cast(u16, h);
}

// async global->LDS, 16B per lane. LDS dest is wave-uniform base + lane*16 (HW rule).
__device__ __forceinline__ void gl2lds16(const void* g, void* l) {
  __builtin_amdgcn_global_load_lds((__attribute__((address_space(1))) void*)(void*)(g),
                                   (__attribute__((address_space(3))) void*)(l),
                                   16, 0, 0);
}

// ---------------- routing: histogram + prefix + scatter + tile table ----------------
__global__ void k_route(const int* __restrict__ idx, const float* __restrict__ w,
                        int* __restrict__ slot_tok, float* __restrict__ slot_w,
                        int* __restrict__ tinfo) {
  __shared__ int hist[NE], cur[NE];
  int t = threadIdx.x;
  if (t < NE) hist[t] = 0;
  __syncthreads();
  for (int p = t; p < NP; p += 256) atomicAdd(&hist[idx[p]], 1);
  __syncthreads();
  if (t == 0) {
    int acc = 0, nt = 0;
    for (int e = 0; e < NE; ++e) {
      int c = hist[e];
      cur[e] = acc;
      for (int m = 0; m < c; m += 128) {
        tinfo[1 + nt*3 + 0] = e;
        tinfo[1 + nt*3 + 1] = acc + m;
        tinfo[1 + nt*3 + 2] = (c - m < 128) ? (c - m) : 128;
        ++nt;
      }
      acc += c;
    }
    tinfo[0] = nt;
  }
  __syncthreads();
  for (int p = t; p < NP; p += 256) {
    int e = idx[p];
    int s = atomicAdd(&cur[e], 1);
    slot_tok[s] = p >> 2;      // token index
    slot_w[s]   = w[p];
  }
}

// ---------------- gather token rows -> fp16, expert-sorted ----------------
__global__ void k_gather(const float* __restrict__ x, const int* __restrict__ slot_tok,
                         u16* __restrict__ xs) {
  int s = blockIdx.x;
  int tok = slot_tok[s];
  const float* src = x + (size_t)tok * HD;
  u16* dst = xs + (size_t)s * HD;
  int c = threadIdx.x * 8;
  float4 a = *(const float4*)(src + c);
  float4 b = *(const float4*)(src + c + 4);
  u16x8 o;
  o[0]=f2hu(a.x); o[1]=f2hu(a.y); o[2]=f2hu(a.z); o[3]=f2hu(a.w);
  o[4]=f2hu(b.x); o[5]=f2hu(b.y); o[6]=f2hu(b.z); o[7]=f2hu(b.w);
  *(u16x8*)(dst + c) = o;
}

// ---------------- fp32 -> fp16 bulk cast (weights) ----------------
__global__ void k_cvt(const float* __restrict__ s, u16* __restrict__ d, int n) {
  long i = ((long)blockIdx.x * blockDim.x + threadIdx.x) * 8;
  long stride = (long)gridDim.x * blockDim.x * 8;
  for (; i < n; i += stride) {
    float4 a = *(const float4*)(s + i);
    float4 b = *(const float4*)(s + i + 4);
    u16x8 o;
    o[0]=f2hu(a.x); o[1]=f2hu(a.y); o[2]=f2hu(a.z); o[3]=f2hu(a.w);
    o[4]=f2hu(b.x); o[5]=f2hu(b.y); o[6]=f2hu(b.z); o[7]=f2hu(b.w);
    *(u16x8*)(d + i) = o;
  }
}

// ---------------- fused gate+up grouped GEMM -> hact = silu(g)*u (fp16) -------------
// 128x128 tile, BK=64, 4 waves (2x2 of 64x64), 16x16x32 f16 MFMA.
// LDS staged via global_load_lds w=16; global chunk column XOR-swizzled by (row&7) so
// fragment ds_read_b128 lands max 2-way on banks (free).
// Grid: 1D, 880 blocks. Logical order = N-tile major / M-tile fastest, so the ~5
// M-tiles of one expert run that share a weight slice are dispatch-adjacent; the
// bijective XCD-chunk swizzle (880 = 8*110) keeps them on one XCD's L2 (T1).
__global__ __launch_bounds__(256, 2)
void k_gateup(const u16* __restrict__ xs, const u16* __restrict__ wg,
              const u16* __restrict__ wu, u16* __restrict__ hact,
              const int* __restrict__ tinfo) {
  int flat = blockIdx.x;
  int swz  = (flat & 7) * 110 + (flat >> 3);   // per-XCD contiguous chunks
  int mt   = swz % 80;                          // M-tile (fastest)
  int nt   = swz / 80;                          // N-tile
  if (mt >= tinfo[0]) return;
  int e  = tinfo[1 + mt*3 + 0];
  int m0 = tinfo[1 + mt*3 + 1];
  int mc = tinfo[1 + mt*3 + 2];
  int n0 = nt * 128;

  const u16* wgb = wg + (size_t)e * ID * HD;
  const u16* wub = wu + (size_t)e * ID * HD;

  __shared__ __align__(16) char As[128*64*2];
  __shared__ __align__(16) char Gs[128*64*2];
  __shared__ __align__(16) char Us[128*64*2];

  int t = threadIdx.x;
  int lane = t & 63, wave = t >> 6;
  int wm = (wave >> 1) * 64, wn = (wave & 1) * 64;
  int rlo = lane & 15, quad = lane >> 4;

  // staging source pointers (4 rounds x 3 matrices), XOR-swizzled chunk column
  const u16* pA[4]; const u16* pG[4]; const u16* pU[4];
#pragma unroll
  for (int r = 0; r < 4; ++r) {
    int row = r*32 + (t >> 3);
    int cg  = (t & 7) ^ (row & 7);
    int ar  = row < mc ? row : mc - 1;   // clamp partial M tile (dup rows, discarded at epilogue)
    pA[r] = xs  + (size_t)(m0 + ar)  * HD + cg*8;
    pG[r] = wgb + (size_t)(n0 + row) * HD + cg*8;
    pU[r] = wub + (size_t)(n0 + row) * HD + cg*8;
  }
  int ldsu = wave * 1024;   // wave-uniform LDS base; HW adds lane*16

  f32x4 accg[4][4], accu[4][4];
  const f32x4 fz = {0.f, 0.f, 0.f, 0.f};
#pragma unroll
  for (int i = 0; i < 4; ++i)
#pragma unroll
    for (int j = 0; j < 4; ++j) { accg[i][j] = fz; accu[i][j] = fz; }

  for (int kt = 0; kt < HD; kt += 64) {
#pragma unroll
    for (int r = 0; r < 4; ++r) {
      gl2lds16(pA[r] + kt, As + r*4096 + ldsu);
      gl2lds16(pG[r] + kt, Gs + r*4096 + ldsu);
      gl2lds16(pU[r] + kt, Us + r*4096 + ldsu);
    }
    __builtin_amdgcn_s_waitcnt(0);
    __syncthreads();

#pragma unroll
    for (int ks = 0; ks < 2; ++ks) {
      f16x8 av[4], gv[4], uv[4];
#pragma unroll
      for (int f = 0; f < 4; ++f) {
        int rA = wm + f*16 + rlo;
        int rB = wn + f*16 + rlo;
        int cA = (((ks*4 + quad) ^ (rA & 7))) * 16;
        int cB = (((ks*4 + quad) ^ (rB & 7))) * 16;
        av[f] = *(const f16x8*)(As + rA*128 + cA);
        gv[f] = *(const f16x8*)(Gs + rB*128 + cB);
        uv[f] = *(const f16x8*)(Us + rB*128 + cB);
      }
#pragma unroll
      for (int fm = 0; fm < 4; ++fm)
#pragma unroll
        for (int fn = 0; fn < 4; ++fn) {
          accg[fm][fn] = __builtin_amdgcn_mfma_f32_16x16x32_f16(av[fm], gv[fn], accg[fm][fn], 0, 0, 0);
          accu[fm][fn] = __builtin_amdgcn_mfma_f32_16x16x32_f16(av[fm], uv[fn], accu[fm][fn], 0, 0, 0);
        }
    }
    __syncthreads();
  }

  // epilogue: D[m = quad*4+rr][n = lane&15]; hact = silu(g)*u in fp16
#pragma unroll
  for (int fm = 0; fm < 4; ++fm) {
    int mb = wm + fm*16 + quad*4;
#pragma unroll
    for (int rr = 0; rr < 4; ++rr) {
      int m = mb + rr;
      if (m < mc) {
        u16* drow = hact + (size_t)(m0 + m) * ID + n0 + wn + rlo;
#pragma unroll
        for (int fn = 0; fn < 4; ++fn) {
          float g = accg[fm][fn][rr];
          float u = accu[fm][fn][rr];
          float hv = (g / (1.f + __expf(-g))) * u;
          drow[fn*16] = f2hu(hv);
        }
      }
    }
  }
}

// ---------------- down grouped GEMM + weighted atomic scatter-combine ----------------
// Same T1 treatment: 1280 = 8*160 blocks, M-tile fastest.
// 3 waves/EU: acc is 64 AGPR + ~108 arch VGPR -> fits 170/wave, gives 3 blocks/CU.
__global__ __launch_bounds__(256, 3)
void k_down(const u16* __restrict__ ha, const u16* __restrict__ wd,
            float* __restrict__ out, const int* __restrict__ slot_tok,
            const float* __restrict__ slot_w, const int* __restrict__ tinfo) {
  int flat = blockIdx.x;
  int swz  = (flat & 7) * 160 + (flat >> 3);
  int mt   = swz % 80;
  int nt   = swz / 80;
  if (mt >= tinfo[0]) return;
  int e  = tinfo[1 + mt*3 + 0];
  int m0 = tinfo[1 + mt*3 + 1];
  int mc = tinfo[1 + mt*3 + 2];
  int n0 = nt * 128;

  const u16* wb = wd + (size_t)e * HD * ID;

  __shared__ __align__(16) char As[128*64*2];
  __shared__ __align__(16) char Bs[128*64*2];

  int t = threadIdx.x;
  int lane = t & 63, wave = t >> 6;
  int wm = (wave >> 1) * 64, wn = (wave & 1) * 64;
  int rlo = lane & 15, quad = lane >> 4;

  const u16* pA[4]; const u16* pB[4];
#pragma unroll
  for (int r = 0; r < 4; ++r) {
    int row = r*32 + (t >> 3);
    int cg  = (t & 7) ^ (row & 7);
    int ar  = row < mc ? row : mc - 1;
    pA[r] = ha + (size_t)(m0 + ar)  * ID + cg*8;
    pB[r] = wb + (size_t)(n0 + row) * ID + cg*8;
  }
  int ldsu = wave * 1024;

  f32x4 acc[4][4];
  const f32x4 fz = {0.f, 0.f, 0.f, 0.f};
#pragma unroll
  for (int i = 0; i < 4; ++i)
#pragma unroll
    for (int j = 0; j < 4; ++j) acc[i][j] = fz;

  for (int kt = 0; kt < ID; kt += 64) {
#pragma unroll
    for (int r = 0; r < 4; ++r) {
      gl2lds16(pA[r] + kt, As + r*4096 + ldsu);
      gl2lds16(pB[r] + kt, Bs + r*4096 + ldsu);
    }
    __builtin_amdgcn_s_waitcnt(0);
    __syncthreads();

#pragma unroll
    for (int ks = 0; ks < 2; ++ks) {
      f16x8 av[4], bv[4];
#pragma unroll
      for (int f = 0; f < 4; ++f) {
        int rA = wm + f*16 + rlo;
        int rB = wn + f*16 + rlo;
        int cA = (((ks*4 + quad) ^ (rA & 7))) * 16;
        int cB = (((ks*4 + quad) ^ (rB & 7))) * 16;
        av[f] = *(const f16x8*)(As + rA*128 + cA);
        bv[f] = *(const f16x8*)(Bs + rB*128 + cB);
      }
#pragma unroll
      for (int fm = 0; fm < 4; ++fm)
#pragma unroll
        for (int fn = 0; fn < 4; ++fn)
          acc[fm][fn] = __builtin_amdgcn_mfma_f32_16x16x32_f16(av[fm], bv[fn], acc[fm][fn], 0, 0, 0);
    }
    __syncthreads();
  }

#pragma unroll
  for (int fm = 0; fm < 4; ++fm) {
    int mb = wm + fm*16 + quad*4;
#pragma unroll
    for (int rr = 0; rr < 4; ++rr) {
      int m = mb + rr;
      if (m < mc) {
        int s = m0 + m;
        int tok = slot_tok[s];
        float w = slot_w[s];
        float* orow = out + (size_t)tok * HD + n0 + wn + rlo;
#pragma unroll
        for (int fn = 0; fn < 4; ++fn)
          atomicAdd(orow + fn*16, acc[fm][fn][rr] * w);
      }
    }
  }
}

// ---------------- launch ----------------
extern "C" void kernel_launch(void* const* d_in, const int* in_sizes, int n_in,
                              void* d_out, int out_size, void* d_ws, size_t ws_size,
                              hipStream_t stream) {
  (void)in_sizes; (void)n_in; (void)out_size; (void)ws_size;
  const float* hs   = (const float*)d_in[0];
  const int*   tidx = (const int*)d_in[1];
  const float* tw   = (const float*)d_in[2];
  const float* gw   = (const float*)d_in[3];
  const float* uw   = (const float*)d_in[4];
  const float* dw   = (const float*)d_in[5];
  float* out = (float*)d_out;

  char* ws = (char*)d_ws;
  size_t off = 0;
  auto carve = [&](size_t b) { char* p = ws + off; off += (b + 255) & ~(size_t)255; return p; };
  u16* xs    = (u16*)carve((size_t)NP * HD * 2);        // 32 MB
  u16* wgh   = (u16*)carve((size_t)NE * ID * HD * 2);   // 88 MB
  u16* wuh   = (u16*)carve((size_t)NE * ID * HD * 2);   // 88 MB
  u16* wdh   = (u16*)carve((size_t)NE * HD * ID * 2);   // 88 MB
  u16* hact  = (u16*)carve((size_t)NP * ID * 2);        // 22 MB
  int*   slot_tok = (int*)carve((size_t)NP * 4);
  float* slot_w   = (float*)carve((size_t)NP * 4);
  int*   tinfo    = (int*)carve((size_t)(1 + MAXT*3) * 4);

  hipMemsetAsync(out, 0, (size_t)NTOK * HD * 4, stream);
  k_route<<<1, 256, 0, stream>>>(tidx, tw, slot_tok, slot_w, tinfo);
  int wn_el = NE * ID * HD;
  // Convert down-weights FIRST so gate/up fp16 weights (written last) are still
  // LLC-resident when k_gateup streams them; gather xs right before gateup.
  k_cvt<<<4096, 256, 0, stream>>>(dw, wdh, wn_el);
  k_cvt<<<4096, 256, 0, stream>>>(gw, wgh, wn_el);
  k_cvt<<<4096, 256, 0, stream>>>(uw, wuh, wn_el);
  k_gather<<<NP, 256, 0, stream>>>(hs, slot_tok, xs);
  k_gateup<<<dim3(880), 256, 0, stream>>>(xs, wgh, wuh, hact, tinfo);
  k_down  <<<dim3(1280), 256, 0, stream>>>(hact, wdh, out, slot_tok, slot_w, tinfo);
}

// Round 2
// 815.487 us; speedup vs baseline: 1.0337x; 1.0143x over previous
//
#include <hip/hip_runtime.h>

// MoE grouped experts: E=16, H=2048, I=1408, TOPK=4, B*S=2048 tokens, P=8192 rows.
// fp32 in/out; compute in fp16 MFMA (16x16x32), fp32 accumulate.
// Weights are read fp32 directly from HBM and converted to fp16 in-register during
// LDS staging (no separate cvt pass).

#define NE   16
#define HD   2048
#define ID   1408
#define NTOK 2048
#define NP   8192
#define MAXT 96

typedef _Float16 f16x8 __attribute__((ext_vector_type(8)));
typedef float    f32x4 __attribute__((ext_vector_type(4)));
typedef unsigned short u16;
typedef u16      u16x8 __attribute__((ext_vector_type(8)));

__device__ __forceinline__ u16 f2hu(float f) {
  _Float16 h = (_Float16)f;               // RNE
  return __builtin_bit_cast(u16, h);
}

__device__ __forceinline__ f16x8 cvt8(float4 a, float4 b) {
  f16x8 o;
  o[0]=(_Float16)a.x; o[1]=(_Float16)a.y; o[2]=(_Float16)a.z; o[3]=(_Float16)a.w;
  o[4]=(_Float16)b.x; o[5]=(_Float16)b.y; o[6]=(_Float16)b.z; o[7]=(_Float16)b.w;
  return o;
}

// async global->LDS, 16B per lane. LDS dest is wave-uniform base + lane*16 (HW rule).
__device__ __forceinline__ void gl2lds16(const void* g, void* l) {
  __builtin_amdgcn_global_load_lds((__attribute__((address_space(1))) void*)(void*)(g),
                                   (__attribute__((address_space(3))) void*)(l),
                                   16, 0, 0);
}

// ---------------- routing: histogram + prefix + scatter + tile table ----------------
__global__ void k_route(const int* __restrict__ idx, const float* __restrict__ w,
                        int* __restrict__ slot_tok, float* __restrict__ slot_w,
                        int* __restrict__ tinfo) {
  __shared__ int hist[NE], cur[NE];
  int t = threadIdx.x;
  if (t < NE) hist[t] = 0;
  __syncthreads();
  for (int p = t; p < NP; p += 256) atomicAdd(&hist[idx[p]], 1);
  __syncthreads();
  if (t == 0) {
    int acc = 0, nt = 0;
    for (int e = 0; e < NE; ++e) {
      int c = hist[e];
      cur[e] = acc;
      for (int m = 0; m < c; m += 128) {
        tinfo[1 + nt*3 + 0] = e;
        tinfo[1 + nt*3 + 1] = acc + m;
        tinfo[1 + nt*3 + 2] = (c - m < 128) ? (c - m) : 128;
        ++nt;
      }
      acc += c;
    }
    tinfo[0] = nt;
  }
  __syncthreads();
  for (int p = t; p < NP; p += 256) {
    int e = idx[p];
    int s = atomicAdd(&cur[e], 1);
    slot_tok[s] = p >> 2;      // token index
    slot_w[s]   = w[p];
  }
}

// ---------------- gather token rows -> fp16, expert-sorted ----------------
__global__ void k_gather(const float* __restrict__ x, const int* __restrict__ slot_tok,
                         u16* __restrict__ xs) {
  int s = blockIdx.x;
  int tok = slot_tok[s];
  const float* src = x + (size_t)tok * HD;
  u16* dst = xs + (size_t)s * HD;
  int c = threadIdx.x * 8;
  float4 a = *(const float4*)(src + c);
  float4 b = *(const float4*)(src + c + 4);
  u16x8 o;
  o[0]=f2hu(a.x); o[1]=f2hu(a.y); o[2]=f2hu(a.z); o[3]=f2hu(a.w);
  o[4]=f2hu(b.x); o[5]=f2hu(b.y); o[6]=f2hu(b.z); o[7]=f2hu(b.w);
  *(u16x8*)(dst + c) = o;
}

// ---------------- fused gate+up grouped GEMM -> hact = silu(g)*u (fp16) -------------
// 128x128 tile, BK=64, 4 waves (2x2 of 64x64), 16x16x32 f16 MFMA.
// A (xs, fp16) staged via global_load_lds w=16. Weights (fp32) are reg-staged:
// global_load_dwordx4 x2 -> RNE cvt -> ds_write_b128 to the SAME swizzled LDS image
// gl2lds would have produced (dest = r*4096 + t*16), so fragment reads are unchanged.
// Grid: 1D, 880 blocks, M-tile fastest + bijective XCD-chunk swizzle (T1).
__global__ __launch_bounds__(256, 2)
void k_gateup(const u16* __restrict__ xs, const float* __restrict__ wg,
              const float* __restrict__ wu, u16* __restrict__ hact,
              const int* __restrict__ tinfo) {
  int flat = blockIdx.x;
  int swz  = (flat & 7) * 110 + (flat >> 3);   // per-XCD contiguous chunks
  int mt   = swz % 80;                          // M-tile (fastest)
  int nt   = swz / 80;                          // N-tile
  if (mt >= tinfo[0]) return;
  int e  = tinfo[1 + mt*3 + 0];
  int m0 = tinfo[1 + mt*3 + 1];
  int mc = tinfo[1 + mt*3 + 2];
  int n0 = nt * 128;

  const float* wgb = wg + (size_t)e * ID * HD;
  const float* wub = wu + (size_t)e * ID * HD;

  __shared__ __align__(16) char As[128*64*2];
  __shared__ __align__(16) char Gs[128*64*2];
  __shared__ __align__(16) char Us[128*64*2];

  int t = threadIdx.x;
  int lane = t & 63, wave = t >> 6;
  int wm = (wave >> 1) * 64, wn = (wave & 1) * 64;
  int rlo = lane & 15, quad = lane >> 4;

  // staging source pointers (4 rounds), XOR-swizzled chunk column
  const u16* pA[4]; const float* pG[4]; const float* pU[4];
#pragma unroll
  for (int r = 0; r < 4; ++r) {
    int row = r*32 + (t >> 3);
    int cg  = (t & 7) ^ (row & 7);
    int ar  = row < mc ? row : mc - 1;   // clamp partial M tile (dup rows, discarded at epilogue)
    pA[r] = xs  + (size_t)(m0 + ar)  * HD + cg*8;
    pG[r] = wgb + (size_t)(n0 + row) * HD + cg*8;
    pU[r] = wub + (size_t)(n0 + row) * HD + cg*8;
  }
  int ldsu = wave * 1024;   // wave-uniform LDS base; HW adds lane*16

  f32x4 accg[4][4], accu[4][4];
  const f32x4 fz = {0.f, 0.f, 0.f, 0.f};
#pragma unroll
  for (int i = 0; i < 4; ++i)
#pragma unroll
    for (int j = 0; j < 4; ++j) { accg[i][j] = fz; accu[i][j] = fz; }

  for (int kt = 0; kt < HD; kt += 64) {
    // issue async A staging first (overlaps with weight loads)
#pragma unroll
    for (int r = 0; r < 4; ++r)
      gl2lds16(pA[r] + kt, As + r*4096 + ldsu);

    // reg-stage weights: fp32 load -> fp16 cvt
    f16x8 gst[4], ust[4];
#pragma unroll
    for (int r = 0; r < 4; ++r) {
      float4 g0 = *(const float4*)(pG[r] + kt);
      float4 g1 = *(const float4*)(pG[r] + kt + 4);
      float4 u0 = *(const float4*)(pU[r] + kt);
      float4 u1 = *(const float4*)(pU[r] + kt + 4);
      gst[r] = cvt8(g0, g1);
      ust[r] = cvt8(u0, u1);
    }
#pragma unroll
    for (int r = 0; r < 4; ++r) {
      *(f16x8*)(Gs + r*4096 + t*16) = gst[r];
      *(f16x8*)(Us + r*4096 + t*16) = ust[r];
    }
    __builtin_amdgcn_s_waitcnt(0);   // drain gl2lds before barrier
    __syncthreads();

#pragma unroll
    for (int ks = 0; ks < 2; ++ks) {
      f16x8 av[4], gv[4], uv[4];
#pragma unroll
      for (int f = 0; f < 4; ++f) {
        int rA = wm + f*16 + rlo;
        int rB = wn + f*16 + rlo;
        int cA = (((ks*4 + quad) ^ (rA & 7))) * 16;
        int cB = (((ks*4 + quad) ^ (rB & 7))) * 16;
        av[f] = *(const f16x8*)(As + rA*128 + cA);
        gv[f] = *(const f16x8*)(Gs + rB*128 + cB);
        uv[f] = *(const f16x8*)(Us + rB*128 + cB);
      }
#pragma unroll
      for (int fm = 0; fm < 4; ++fm)
#pragma unroll
        for (int fn = 0; fn < 4; ++fn) {
          accg[fm][fn] = __builtin_amdgcn_mfma_f32_16x16x32_f16(av[fm], gv[fn], accg[fm][fn], 0, 0, 0);
          accu[fm][fn] = __builtin_amdgcn_mfma_f32_16x16x32_f16(av[fm], uv[fn], accu[fm][fn], 0, 0, 0);
        }
    }
    __syncthreads();
  }

  // epilogue: D[m = quad*4+rr][n = lane&15]; hact = silu(g)*u in fp16
#pragma unroll
  for (int fm = 0; fm < 4; ++fm) {
    int mb = wm + fm*16 + quad*4;
#pragma unroll
    for (int rr = 0; rr < 4; ++rr) {
      int m = mb + rr;
      if (m < mc) {
        u16* drow = hact + (size_t)(m0 + m) * ID + n0 + wn + rlo;
#pragma unroll
        for (int fn = 0; fn < 4; ++fn) {
          float g = accg[fm][fn][rr];
          float u = accu[fm][fn][rr];
          float hv = (g / (1.f + __expf(-g))) * u;
          drow[fn*16] = f2hu(hv);
        }
      }
    }
  }
}

// ---------------- down grouped GEMM + weighted atomic scatter-combine ----------------
// A (hact fp16) via gl2lds; B (down weight fp32) reg-staged with in-flight cvt.
// 1280 = 8*160 blocks, M-tile fastest + bijective XCD swizzle.
__global__ __launch_bounds__(256, 2)
void k_down(const u16* __restrict__ ha, const float* __restrict__ wd,
            float* __restrict__ out, const int* __restrict__ slot_tok,
            const float* __restrict__ slot_w, const int* __restrict__ tinfo) {
  int flat = blockIdx.x;
  int swz  = (flat & 7) * 160 + (flat >> 3);
  int mt   = swz % 80;
  int nt   = swz / 80;
  if (mt >= tinfo[0]) return;
  int e  = tinfo[1 + mt*3 + 0];
  int m0 = tinfo[1 + mt*3 + 1];
  int mc = tinfo[1 + mt*3 + 2];
  int n0 = nt * 128;

  const float* wb = wd + (size_t)e * HD * ID;

  __shared__ __align__(16) char As[128*64*2];
  __shared__ __align__(16) char Bs[128*64*2];

  int t = threadIdx.x;
  int lane = t & 63, wave = t >> 6;
  int wm = (wave >> 1) * 64, wn = (wave & 1) * 64;
  int rlo = lane & 15, quad = lane >> 4;

  const u16* pA[4]; const float* pB[4];
#pragma unroll
  for (int r = 0; r < 4; ++r) {
    int row = r*32 + (t >> 3);
    int cg  = (t & 7) ^ (row & 7);
    int ar  = row < mc ? row : mc - 1;
    pA[r] = ha + (size_t)(m0 + ar)  * ID + cg*8;
    pB[r] = wb + (size_t)(n0 + row) * ID + cg*8;
  }
  int ldsu = wave * 1024;

  f32x4 acc[4][4];
  const f32x4 fz = {0.f, 0.f, 0.f, 0.f};
#pragma unroll
  for (int i = 0; i < 4; ++i)
#pragma unroll
    for (int j = 0; j < 4; ++j) acc[i][j] = fz;

  for (int kt = 0; kt < ID; kt += 64) {
#pragma unroll
    for (int r = 0; r < 4; ++r)
      gl2lds16(pA[r] + kt, As + r*4096 + ldsu);

    f16x8 bst[4];
#pragma unroll
    for (int r = 0; r < 4; ++r) {
      float4 b0 = *(const float4*)(pB[r] + kt);
      float4 b1 = *(const float4*)(pB[r] + kt + 4);
      bst[r] = cvt8(b0, b1);
    }
#pragma unroll
    for (int r = 0; r < 4; ++r)
      *(f16x8*)(Bs + r*4096 + t*16) = bst[r];

    __builtin_amdgcn_s_waitcnt(0);
    __syncthreads();

#pragma unroll
    for (int ks = 0; ks < 2; ++ks) {
      f16x8 av[4], bv[4];
#pragma unroll
      for (int f = 0; f < 4; ++f) {
        int rA = wm + f*16 + rlo;
        int rB = wn + f*16 + rlo;
        int cA = (((ks*4 + quad) ^ (rA & 7))) * 16;
        int cB = (((ks*4 + quad) ^ (rB & 7))) * 16;
        av[f] = *(const f16x8*)(As + rA*128 + cA);
        bv[f] = *(const f16x8*)(Bs + rB*128 + cB);
      }
#pragma unroll
      for (int fm = 0; fm < 4; ++fm)
#pragma unroll
        for (int fn = 0; fn < 4; ++fn)
          acc[fm][fn] = __builtin_amdgcn_mfma_f32_16x16x32_f16(av[fm], bv[fn], acc[fm][fn], 0, 0, 0);
    }
    __syncthreads();
  }

#pragma unroll
  for (int fm = 0; fm < 4; ++fm) {
    int mb = wm + fm*16 + quad*4;
#pragma unroll
    for (int rr = 0; rr < 4; ++rr) {
      int m = mb + rr;
      if (m < mc) {
        int s = m0 + m;
        int tok = slot_tok[s];
        float w = slot_w[s];
        float* orow = out + (size_t)tok * HD + n0 + wn + rlo;
#pragma unroll
        for (int fn = 0; fn < 4; ++fn)
          atomicAdd(orow + fn*16, acc[fm][fn][rr] * w);
      }
    }
  }
}

// ---------------- launch ----------------
extern "C" void kernel_launch(void* const* d_in, const int* in_sizes, int n_in,
                              void* d_out, int out_size, void* d_ws, size_t ws_size,
                              hipStream_t stream) {
  (void)in_sizes; (void)n_in; (void)out_size; (void)ws_size;
  const float* hs   = (const float*)d_in[0];
  const int*   tidx = (const int*)d_in[1];
  const float* tw   = (const float*)d_in[2];
  const float* gw   = (const float*)d_in[3];
  const float* uw   = (const float*)d_in[4];
  const float* dw   = (const float*)d_in[5];
  float* out = (float*)d_out;

  char* ws = (char*)d_ws;
  size_t off = 0;
  auto carve = [&](size_t b) { char* p = ws + off; off += (b + 255) & ~(size_t)255; return p; };
  u16* xs    = (u16*)carve((size_t)NP * HD * 2);        // 32 MB
  u16* hact  = (u16*)carve((size_t)NP * ID * 2);        // 22 MB
  int*   slot_tok = (int*)carve((size_t)NP * 4);
  float* slot_w   = (float*)carve((size_t)NP * 4);
  int*   tinfo    = (int*)carve((size_t)(1 + MAXT*3) * 4);

  hipMemsetAsync(out, 0, (size_t)NTOK * HD * 4, stream);
  k_route<<<1, 256, 0, stream>>>(tidx, tw, slot_tok, slot_w, tinfo);
  k_gather<<<NP, 256, 0, stream>>>(hs, slot_tok, xs);
  k_gateup<<<dim3(880), 256, 0, stream>>>(xs, gw, uw, hact, tinfo);
  k_down  <<<dim3(1280), 256, 0, stream>>>(hact, dw, out, slot_tok, slot_w, tinfo);
}